// Round 8
// baseline (300.886 us; speedup 1.0000x reference)
//
#include <hip/hip_runtime.h>

// Problem constants (match reference)
#define DHW   (128*128*128)        // 2^21
#define CDHW  (4*DHW)              // 2^23
#define NTOT  (2*CDHW)             // 2^24 = 16,777,216
#define NACC  1024                 // one accumulator slot per block

// erode2 tiling: full x-row (32 f4), 8 owned y-rows, 16 owned z-planes.
#define ROW4    32
#define IN_ROWS 12                 // 8 + 2*2 y-halo
#define S1_ROWS 10                 // 8 + 2*1
#define IN_P4   (IN_ROWS*ROW4)     // 384 f4 / input plane
#define S1_P4   (S1_ROWS*ROW4)     // 320 f4 / s1 plane
#define SLOT(z) (((z)+6)%3)

// TWO fused erosion steps; z-marching rolling planes (R6-proven structure).
// PASS1 fuses softmax+one-hot+square into the prefetch/commit path.
template<int PASS1>
__global__ __launch_bounds__(256, 4) void erode2_kernel(
    const float4* __restrict__ src,      // pass>=2: op buffer
    const float4* __restrict__ rawin,    // pass1: raw logits (B,C,D,H,W)
    const int4*   __restrict__ tgt4,     // pass1: targets (B,D,H,W) int32
    float4* __restrict__ dst,
    const float* __restrict__ kern, const float* __restrict__ bias,
    const float* __restrict__ weight, float c1, float c2,
    int store, double* __restrict__ accs)
{
    __shared__ float4 lin[3 * IN_P4];   // 18.4 KB
    __shared__ float4 ls1[3 * S1_P4];   // 15.4 KB
    __shared__ double wsum[4];

    const int tid = threadIdx.x;
    const int bid = blockIdx.x;
    const int y0 = (bid & 15) << 3;
    const int zb = ((bid >> 4) & 7) << 4;
    const int bc = bid >> 7;            // b*4 + c in [0,8)
    const int b  = bc >> 2;
    const int cc = bc & 3;

    const float4* sp  = src   + ((size_t)bc << 19);  // op slab (2^19 f4)
    float4*       dp  = dst   + ((size_t)bc << 19);
    const float4* inb = rawin + ((size_t)b << 21);   // raw b-slab (f4)
    const int4*   tgb = tgt4  + ((size_t)b << 19);   // target b-slab (int4)
    const float wk = kern[13];          // all 7 taps equal
    const float bs = bias[cc];

    const int col  = tid & 31;
    const int trow = tid >> 5;

    // ---- load maps (input rows 0..11 <-> gy = y0+row-2) ----
    const int  gy0  = y0 + trow - 2;
    const bool lv0  = ((unsigned)gy0 < 128u);
    const int  off0 = (lv0 ? gy0 : 0) * 32 + col;
    const bool act1 = (tid < 128);                 // rows 8..11
    const int  gy1  = y0 + trow + 6;
    const bool lv1  = act1 && ((unsigned)gy1 < 128u);
    const int  off1 = (lv1 ? gy1 : 0) * 32 + col;

    // ---- s1 maps (s1 rows 0..9 <-> gy = y0+r-1) ----
    const float m0  = ((unsigned)(y0 + trow - 1) < 128u) ? 1.f : 0.f;
    const int   ci0 = (trow + 1) * 32 + col;
    const bool  sact1 = (tid < 64);                // s1 rows 8..9
    const int   r1  = 8 + trow;
    const float m1  = ((unsigned)(y0 + r1 - 1) < 128u) ? 1.f : 0.f;
    const int   ci1 = (r1 + 1) * 32 + col;

    const float lmask = (col == 0)  ? 0.f : 1.f;   // x=0 edge
    const float rmask = (col == 31) ? 0.f : 1.f;   // x=127 edge

    // ---- step2 map (owned oy = trow 0..7) ----
    const int cix = (trow + 1) * 32 + col;
    const int go4 = (y0 + trow) * 32 + col;

    const float4 f4z = make_float4(0.f, 0.f, 0.f, 0.f);
    float4 pf0 = f4z, pf1 = f4z;                             // plain prefetch
    float4 pA0 = f4z, pA1 = f4z, pA2 = f4z, pA3 = f4z;       // pass1 primary
    float4 pB0 = f4z, pB1 = f4z, pB2 = f4z, pB3 = f4z;       // pass1 ragged
    int4   pT0 = make_int4(-1, -1, -1, -1), pT1 = pT0;
    float  pm0 = 0.f, pm1 = 0.f;

    auto prefetch = [&](int L) {
        const bool zok = ((unsigned)L < 128u);
        if (PASS1) {
            pm0 = (zok && lv0) ? 1.f : 0.f;
            pm1 = (zok && lv1) ? 1.f : 0.f;
            pA0 = pA1 = pA2 = pA3 = f4z;
            pB0 = pB1 = pB2 = pB3 = f4z;
            if (zok) {
                if (lv0) {
                    const float4* zp = inb + ((size_t)L << 12) + off0;
                    pA0 = zp[0];
                    pA1 = zp[1 << 19];
                    pA2 = zp[2 << 19];
                    pA3 = zp[3 << 19];
                    pT0 = tgb[((size_t)L << 12) + off0];
                }
                if (lv1) {
                    const float4* zq = inb + ((size_t)L << 12) + off1;
                    pB0 = zq[0];
                    pB1 = zq[1 << 19];
                    pB2 = zq[2 << 19];
                    pB3 = zq[3 << 19];
                    pT1 = tgb[((size_t)L << 12) + off1];
                }
            }
        } else {
            pf0 = f4z; pf1 = f4z;
            if (zok) {
                const float4* zp = sp + ((size_t)L << 12);
                if (lv0) pf0 = zp[off0];
                if (lv1) pf1 = zp[off1];
            }
        }
    };

    // softmax residual squared for class cc; mk zeroes out-of-volume lanes
    auto sqsm = [&](float4 a0, float4 a1, float4 a2, float4 a3, int4 t,
                    float mk) -> float4 {
        float4 o;
        #define DO(K)                                                          \
        {                                                                      \
            float m = fmaxf(fmaxf(a0.K, a1.K), fmaxf(a2.K, a3.K));             \
            float e0 = expf(a0.K - m), e1 = expf(a1.K - m);                    \
            float e2 = expf(a2.K - m), e3 = expf(a3.K - m);                    \
            float inv = 1.0f / (e0 + e1 + e2 + e3);                            \
            float ec = (cc == 0) ? e0 : (cc == 1) ? e1 : (cc == 2) ? e2 : e3;  \
            float d = ec * inv - ((t.K == cc) ? 1.0f : 0.0f);                  \
            o.K = d * d * mk;                                                  \
        }
        DO(x) DO(y) DO(z) DO(w)
        #undef DO
        return o;
    };

    auto commit = [&](int L) {
        float4* sl = lin + SLOT(L) * IN_P4;
        if (PASS1) {
            sl[tid] = sqsm(pA0, pA1, pA2, pA3, pT0, pm0);
            if (act1) sl[256 + tid] = sqsm(pB0, pB1, pB2, pB3, pT1, pm1);
        } else {
            sl[tid] = pf0;
            if (act1) sl[256 + tid] = pf1;
        }
    };

    auto s1one = [&](const float4* pzm, const float4* pzc, const float4* pzp,
                     int ci, float ym) -> float4 {
        float4 qC = pzc[ci];
        float4 qL = pzc[ci - 1];
        float4 qR = pzc[ci + 1];
        float4 qU = pzc[ci - 32];
        float4 qD = pzc[ci + 32];
        float4 qm = pzm[ci];
        float4 qp = pzp[ci];
        float lf = qL.w * lmask;
        float rt = qR.x * rmask;
        float4 v;
        v.x = fmaxf((qC.x + lf   + qC.y + qU.x + qD.x + qm.x + qp.x) * wk + bs, 0.f) * ym;
        v.y = fmaxf((qC.y + qC.x + qC.z + qU.y + qD.y + qm.y + qp.y) * wk + bs, 0.f) * ym;
        v.z = fmaxf((qC.z + qC.y + qC.w + qU.z + qD.z + qm.z + qp.z) * wk + bs, 0.f) * ym;
        v.w = fmaxf((qC.w + qC.z + rt   + qU.w + qD.w + qm.w + qp.w) * wk + bs, 0.f) * ym;
        return v;
    };

    auto s1_plane = [&](int z) {
        float4* o = ls1 + SLOT(z) * S1_P4;
        if ((unsigned)z < 128u) {
            const float4* pzm = lin + SLOT(z - 1) * IN_P4;
            const float4* pzc = lin + SLOT(z)     * IN_P4;
            const float4* pzp = lin + SLOT(z + 1) * IN_P4;
            o[tid] = s1one(pzm, pzc, pzp, ci0, m0);
            if (sact1) o[256 + tid] = s1one(pzm, pzc, pzp, ci1, m1);
        } else {
            o[tid] = f4z;
            if (sact1) o[256 + tid] = f4z;
        }
    };

    double part = 0.0;

    // ---- prologue ----
    prefetch(zb - 2); commit(zb - 2);
    prefetch(zb - 1); commit(zb - 1);
    prefetch(zb);     commit(zb);
    prefetch(zb + 1);                       // stays in regs
    __syncthreads();
    s1_plane(zb - 1);
    __syncthreads();

    // ---- main loop: L = plane committed this iter ----
    for (int L = zb + 1; L <= zb + 17; ++L) {
        commit(L);                          // regs from last iter's prefetch
        if (L <= zb + 16) prefetch(L + 1);  // issue next load, no wait
        __syncthreads();
        s1_plane(L - 1);                    // reads lin L-2..L
        __syncthreads();
        int zo = L - 2;                     // s1 ring holds L-3..L-1
        if (zo >= zb) {
            const float4* szm = ls1 + SLOT(zo - 1) * S1_P4;
            const float4* szc = ls1 + SLOT(zo)     * S1_P4;
            const float4* szp = ls1 + SLOT(zo + 1) * S1_P4;
            float4 c4 = szc[cix];
            float4 l4 = szc[cix - 1];
            float4 r4 = szc[cix + 1];
            float4 u4 = szc[cix - 32];
            float4 d4 = szc[cix + 32];
            float4 m4 = szm[cix];
            float4 p4 = szp[cix];
            float lf = l4.w * lmask;
            float rt = r4.x * rmask;
            float4 v;
            v.x = fmaxf((c4.x + lf   + c4.y + u4.x + d4.x + m4.x + p4.x) * wk + bs, 0.f);
            v.y = fmaxf((c4.y + c4.x + c4.z + u4.y + d4.y + m4.y + p4.y) * wk + bs, 0.f);
            v.z = fmaxf((c4.z + c4.y + c4.w + u4.z + d4.z + m4.z + p4.z) * wk + bs, 0.f);
            v.w = fmaxf((c4.w + c4.z + rt   + u4.w + d4.w + m4.w + p4.w) * wk + bs, 0.f);
            if (store) dp[((size_t)zo << 12) + go4] = v;
            // per-plane f32 partial, one f64 add per plane
            float pl = c1 * (c4.x + c4.y + c4.z + c4.w)
                     + c2 * (v.x  + v.y  + v.z  + v.w);
            part += (double)pl;
        }
    }

    // ---- block reduction; slot bid is private to this block ----
    #pragma unroll
    for (int off = 32; off > 0; off >>= 1)
        part += __shfl_down(part, off, 64);
    if ((tid & 63) == 0) wsum[tid >> 6] = part;
    __syncthreads();
    if (tid == 0) {
        double tot = (wsum[0] + wsum[1] + wsum[2] + wsum[3]) * (double)weight[bc];
        if (PASS1) accs[bid] = tot;            // init (ws is poisoned)
        else       atomicAdd(&accs[bid], tot); // contention-free (private slot)
    }
}

// Reduce the NACC per-block accumulators -> scalar mean.
__global__ __launch_bounds__(1024) void finalize_kernel(
    const double* __restrict__ accs, float* __restrict__ out)
{
    __shared__ double wsum[16];
    double v = accs[threadIdx.x];
    #pragma unroll
    for (int off = 32; off > 0; off >>= 1)
        v += __shfl_down(v, off, 64);
    int lane = threadIdx.x & 63;
    int wid  = threadIdx.x >> 6;
    if (lane == 0) wsum[wid] = v;
    __syncthreads();
    if (threadIdx.x == 0) {
        double tot = 0.0;
        #pragma unroll
        for (int i = 0; i < 16; ++i) tot += wsum[i];
        out[0] = (float)(tot / (double)NTOT);
    }
}

extern "C" void kernel_launch(void* const* d_in, const int* in_sizes, int n_in,
                              void* d_out, int out_size, void* d_ws, size_t ws_size,
                              hipStream_t stream) {
    const float4* in4    = (const float4*)d_in[0];
    const int4*   tg4    = (const int4*)d_in[1];
    const float*  weight = (const float*)d_in[2];
    const float*  kern   = (const float*)d_in[3];
    const float*  bias   = (const float*)d_in[4];
    float* out = (float*)d_out;

    char* ws = (char*)d_ws;
    float4* buf0 = (float4*)ws;
    float4* buf1 = (float4*)(ws + (size_t)NTOT * sizeof(float));
    double* accs = (double*)(ws + (size_t)NTOT * 2 * sizeof(float));

    // pass 1: fused softmax+sq + erosion steps 1,2 (writes accs slots directly)
    erode2_kernel<1><<<1024, 256, 0, stream>>>(
        buf1, in4, tg4, buf0, kern, bias, weight, 1.f, 4.f, 1, accs);
    // passes 2..5: erosion steps 3..10; last pass skips the store
    erode2_kernel<0><<<1024, 256, 0, stream>>>(
        buf0, in4, tg4, buf1, kern, bias, weight, 9.f, 16.f, 1, accs);
    erode2_kernel<0><<<1024, 256, 0, stream>>>(
        buf1, in4, tg4, buf0, kern, bias, weight, 25.f, 36.f, 1, accs);
    erode2_kernel<0><<<1024, 256, 0, stream>>>(
        buf0, in4, tg4, buf1, kern, bias, weight, 49.f, 64.f, 1, accs);
    erode2_kernel<0><<<1024, 256, 0, stream>>>(
        buf1, in4, tg4, buf0, kern, bias, weight, 81.f, 100.f, 0, accs);

    finalize_kernel<<<1, 1024, 0, stream>>>(accs, out);
}

// Round 9
// 253.380 us; speedup vs baseline: 1.1875x; 1.1875x over previous
//
#include <hip/hip_runtime.h>

// Problem constants (match reference)
#define DHW   (128*128*128)        // 2^21
#define CDHW  (4*DHW)              // 2^23
#define NTOT  (2*CDHW)             // 2^24 = 16,777,216
#define NSITE (2*DHW)              // B*DHW = 2^22 sites
#define NACC  1024                 // one accumulator slot per erode block

// erode2 tiling: full x-row (32 f4), 8 owned y-rows, 16 owned z-planes.
#define ROW4    32
#define IN_ROWS 12                 // 8 + 2*2 y-halo
#define S1_ROWS 10                 // 8 + 2*1
#define IN_P4   (IN_ROWS*ROW4)     // 384 f4 / input plane
#define S1_P4   (S1_ROWS*ROW4)     // 320 f4 / s1 plane
#define SLOT(z) (((z)+6)%3)

// Kernel A: softmax over C=4, subtract one-hot(target), square -> buf0.
// 4 float4 site-groups per thread for memory-level parallelism. Zeros accs.
__global__ __launch_bounds__(256) void softmax_sq_kernel(
    const float* __restrict__ in, const int* __restrict__ tgt,
    float* __restrict__ out, double* __restrict__ accs)
{
    int tid = threadIdx.x;
    int gid = blockIdx.x * 256 + tid;
    if (gid < NACC) accs[gid] = 0.0;

    #pragma unroll
    for (int half = 0; half < 4; ++half) {
        int j4 = blockIdx.x * 1024 + half * 256 + tid;  // [0, NSITE/4)
        int base = j4 << 2;
        int b = base >> 21;
        int s = base & (DHW - 1);
        const float* p = in + (size_t)b * CDHW + s;

        float4 a0 = *(const float4*)(p);
        float4 a1 = *(const float4*)(p + DHW);
        float4 a2 = *(const float4*)(p + 2 * DHW);
        float4 a3 = *(const float4*)(p + 3 * DHW);
        int4   t  = *(const int4*)(tgt + base);

        float4 o0, o1, o2, o3;
        #define SOFTMAX1(K)                                                    \
        {                                                                      \
            float v0 = a0.K, v1 = a1.K, v2 = a2.K, v3 = a3.K;                  \
            float m  = fmaxf(fmaxf(v0, v1), fmaxf(v2, v3));                    \
            float e0 = expf(v0 - m), e1 = expf(v1 - m);                        \
            float e2 = expf(v2 - m), e3 = expf(v3 - m);                        \
            float inv = 1.0f / (e0 + e1 + e2 + e3);                            \
            int   tv = t.K;                                                    \
            float d0 = e0 * inv - (tv == 0 ? 1.0f : 0.0f);                     \
            float d1 = e1 * inv - (tv == 1 ? 1.0f : 0.0f);                     \
            float d2 = e2 * inv - (tv == 2 ? 1.0f : 0.0f);                     \
            float d3 = e3 * inv - (tv == 3 ? 1.0f : 0.0f);                     \
            o0.K = d0 * d0; o1.K = d1 * d1; o2.K = d2 * d2; o3.K = d3 * d3;    \
        }
        SOFTMAX1(x) SOFTMAX1(y) SOFTMAX1(z) SOFTMAX1(w)
        #undef SOFTMAX1

        float* q = out + (size_t)b * CDHW + s;
        *(float4*)(q)           = o0;
        *(float4*)(q + DHW)     = o1;
        *(float4*)(q + 2 * DHW) = o2;
        *(float4*)(q + 3 * DHW) = o3;
    }
}

// Kernel B: TWO fused erosion steps; R6-proven z-marching rolling planes.
// x-neighbor values come from lane shuffles instead of LDS reads (saves 4 of
// the 18.5 wave-b128 LDS ops per point; shuffle artifacts at row boundaries
// land exactly on col 0/31 lanes which lmask/rmask already zero).
__global__ __launch_bounds__(256, 4) void erode2_kernel(
    const float4* __restrict__ src, float4* __restrict__ dst,
    const float* __restrict__ kern, const float* __restrict__ bias,
    const float* __restrict__ weight, float c1, float c2,
    int store, double* __restrict__ accs)
{
    __shared__ float4 lin[3 * IN_P4];   // 18.4 KB
    __shared__ float4 ls1[3 * S1_P4];   // 15.4 KB
    __shared__ double wsum[4];

    const int tid = threadIdx.x;
    const int bid = blockIdx.x;
    const int y0 = (bid & 15) << 3;
    const int zb = ((bid >> 4) & 7) << 4;
    const int bc = bid >> 7;            // b*4 + c in [0,8)

    const float4* sp = src + ((size_t)bc << 19);   // slab = 2^19 f4
    float4*       dp = dst + ((size_t)bc << 19);
    const float wk = kern[13];          // all 7 taps equal
    const float bs = bias[bc & 3];

    const int col  = tid & 31;
    const int trow = tid >> 5;

    // ---- load maps (input rows 0..11 <-> gy = y0+row-2) ----
    const int  gy0  = y0 + trow - 2;
    const bool lv0  = ((unsigned)gy0 < 128u);
    const int  off0 = (lv0 ? gy0 : 0) * 32 + col;
    const bool act1 = (tid < 128);                 // rows 8..11
    const int  gy1  = y0 + trow + 6;
    const bool lv1  = act1 && ((unsigned)gy1 < 128u);
    const int  off1 = (lv1 ? gy1 : 0) * 32 + col;

    // ---- s1 maps (s1 rows 0..9 <-> gy = y0+r-1) ----
    const float m0  = ((unsigned)(y0 + trow - 1) < 128u) ? 1.f : 0.f;
    const int   ci0 = (trow + 1) * 32 + col;
    const bool  sact1 = (tid < 64);                // s1 rows 8..9
    const int   r1  = 8 + trow;
    const float m1  = ((unsigned)(y0 + r1 - 1) < 128u) ? 1.f : 0.f;
    const int   ci1 = (r1 + 1) * 32 + col;

    const float lmask = (col == 0)  ? 0.f : 1.f;   // x=0 edge
    const float rmask = (col == 31) ? 0.f : 1.f;   // x=127 edge

    // ---- step2 map (owned oy = trow 0..7) ----
    const int cix = (trow + 1) * 32 + col;
    const int go4 = (y0 + trow) * 32 + col;

    const float4 f4z = make_float4(0.f, 0.f, 0.f, 0.f);
    float4 pf0 = f4z, pf1 = f4z;

    auto prefetch = [&](int L) {
        pf0 = f4z; pf1 = f4z;
        if ((unsigned)L < 128u) {
            const float4* zp = sp + ((size_t)L << 12);
            if (lv0) pf0 = zp[off0];
            if (lv1) pf1 = zp[off1];
        }
    };
    auto commit = [&](int L) {
        float4* sl = lin + SLOT(L) * IN_P4;
        sl[tid] = pf0;
        if (act1) sl[256 + tid] = pf1;
    };
    auto s1one = [&](const float4* pzm, const float4* pzc, const float4* pzp,
                     int ci, float ym) -> float4 {
        float4 qC = pzc[ci];
        float4 qU = pzc[ci - 32];
        float4 qD = pzc[ci + 32];
        float4 qm = pzm[ci];
        float4 qp = pzp[ci];
        float lf = __shfl_up(qC.w, 1, 64)   * lmask;   // x-neighbors via shuffle
        float rt = __shfl_down(qC.x, 1, 64) * rmask;
        float4 v;
        v.x = fmaxf((qC.x + lf   + qC.y + qU.x + qD.x + qm.x + qp.x) * wk + bs, 0.f) * ym;
        v.y = fmaxf((qC.y + qC.x + qC.z + qU.y + qD.y + qm.y + qp.y) * wk + bs, 0.f) * ym;
        v.z = fmaxf((qC.z + qC.y + qC.w + qU.z + qD.z + qm.z + qp.z) * wk + bs, 0.f) * ym;
        v.w = fmaxf((qC.w + qC.z + rt   + qU.w + qD.w + qm.w + qp.w) * wk + bs, 0.f) * ym;
        return v;
    };
    auto s1_plane = [&](int z) {
        float4* o = ls1 + SLOT(z) * S1_P4;
        if ((unsigned)z < 128u) {
            const float4* pzm = lin + SLOT(z - 1) * IN_P4;
            const float4* pzc = lin + SLOT(z)     * IN_P4;
            const float4* pzp = lin + SLOT(z + 1) * IN_P4;
            o[tid] = s1one(pzm, pzc, pzp, ci0, m0);
            if (sact1) o[256 + tid] = s1one(pzm, pzc, pzp, ci1, m1);
        } else {
            o[tid] = f4z;
            if (sact1) o[256 + tid] = f4z;
        }
    };

    double part = 0.0;

    // ---- prologue ----
    prefetch(zb - 2); commit(zb - 2);
    prefetch(zb - 1); commit(zb - 1);
    prefetch(zb);     commit(zb);
    prefetch(zb + 1);                       // stays in regs
    __syncthreads();
    s1_plane(zb - 1);
    __syncthreads();

    // ---- main loop: L = plane committed this iter ----
    for (int L = zb + 1; L <= zb + 17; ++L) {
        commit(L);                          // regs from last iter's prefetch
        if (L <= zb + 16) prefetch(L + 1);  // issue next load, no wait
        __syncthreads();
        s1_plane(L - 1);                    // reads lin L-2..L
        __syncthreads();
        int zo = L - 2;                     // s1 ring holds L-3..L-1
        if (zo >= zb) {
            const float4* szm = ls1 + SLOT(zo - 1) * S1_P4;
            const float4* szc = ls1 + SLOT(zo)     * S1_P4;
            const float4* szp = ls1 + SLOT(zo + 1) * S1_P4;
            float4 c4 = szc[cix];
            float4 u4 = szc[cix - 32];
            float4 d4 = szc[cix + 32];
            float4 m4 = szm[cix];
            float4 p4 = szp[cix];
            float lf = __shfl_up(c4.w, 1, 64)   * lmask;
            float rt = __shfl_down(c4.x, 1, 64) * rmask;
            float4 v;
            v.x = fmaxf((c4.x + lf   + c4.y + u4.x + d4.x + m4.x + p4.x) * wk + bs, 0.f);
            v.y = fmaxf((c4.y + c4.x + c4.z + u4.y + d4.y + m4.y + p4.y) * wk + bs, 0.f);
            v.z = fmaxf((c4.z + c4.y + c4.w + u4.z + d4.z + m4.z + p4.z) * wk + bs, 0.f);
            v.w = fmaxf((c4.w + c4.z + rt   + u4.w + d4.w + m4.w + p4.w) * wk + bs, 0.f);
            if (store) dp[((size_t)zo << 12) + go4] = v;
            // per-plane f32 partial, one f64 add per plane
            float pl = c1 * (c4.x + c4.y + c4.z + c4.w)
                     + c2 * (v.x  + v.y  + v.z  + v.w);
            part += (double)pl;
        }
    }

    // ---- block reduction; slot bid is private to this block ----
    #pragma unroll
    for (int off = 32; off > 0; off >>= 1)
        part += __shfl_down(part, off, 64);
    if ((tid & 63) == 0) wsum[tid >> 6] = part;
    __syncthreads();
    if (tid == 0) {
        double tot = (wsum[0] + wsum[1] + wsum[2] + wsum[3]) * (double)weight[bc];
        atomicAdd(&accs[bid], tot);         // contention-free (private slot)
    }
}

// Reduce the NACC per-block accumulators -> scalar mean.
__global__ __launch_bounds__(1024) void finalize_kernel(
    const double* __restrict__ accs, float* __restrict__ out)
{
    __shared__ double wsum[16];
    double v = accs[threadIdx.x];
    #pragma unroll
    for (int off = 32; off > 0; off >>= 1)
        v += __shfl_down(v, off, 64);
    int lane = threadIdx.x & 63;
    int wid  = threadIdx.x >> 6;
    if (lane == 0) wsum[wid] = v;
    __syncthreads();
    if (threadIdx.x == 0) {
        double tot = 0.0;
        #pragma unroll
        for (int i = 0; i < 16; ++i) tot += wsum[i];
        out[0] = (float)(tot / (double)NTOT);
    }
}

extern "C" void kernel_launch(void* const* d_in, const int* in_sizes, int n_in,
                              void* d_out, int out_size, void* d_ws, size_t ws_size,
                              hipStream_t stream) {
    const float* in     = (const float*)d_in[0];
    const int*   tgt    = (const int*)d_in[1];
    const float* weight = (const float*)d_in[2];
    const float* kern   = (const float*)d_in[3];
    const float* bias   = (const float*)d_in[4];
    float* out = (float*)d_out;

    char* ws = (char*)d_ws;
    float* buf0 = (float*)ws;
    float* buf1 = (float*)(ws + (size_t)NTOT * sizeof(float));
    double* accs = (double*)(ws + (size_t)NTOT * 2 * sizeof(float));

    // 1) softmax + one-hot + square (also zeroes accs); 4 f4 per thread
    softmax_sq_kernel<<<(NSITE / 16) / 256, 256, 0, stream>>>(in, tgt, buf0, accs);

    // 2) 5 fused double-erosion passes; last pass skips the store
    float* cur = buf0;
    float* nxt = buf1;
    for (int p = 0; p < 5; ++p) {
        float c1 = (float)((2 * p + 1) * (2 * p + 1));
        float c2 = (float)((2 * p + 2) * (2 * p + 2));
        int   store = (p < 4) ? 1 : 0;
        erode2_kernel<<<1024, 256, 0, stream>>>(
            (const float4*)cur, (float4*)nxt, kern, bias, weight, c1, c2, store, accs);
        float* t = cur; cur = nxt; nxt = t;
    }

    // 3) reduce + mean
    finalize_kernel<<<1, 1024, 0, stream>>>(accs, out);
}

// Round 10
// 246.550 us; speedup vs baseline: 1.2204x; 1.0277x over previous
//
#include <hip/hip_runtime.h>

// Problem constants (match reference)
#define DHW   (128*128*128)        // 2^21
#define CDHW  (4*DHW)              // 2^23
#define NTOT  (2*CDHW)             // 2^24 = 16,777,216
#define NSITE (2*DHW)              // B*DHW = 2^22 sites
#define NACC  1024                 // one accumulator slot per erode block

// erode2 tiling: full x-row (32 f4), 8 owned y-rows, 16 owned z-planes.
#define ROW4     32
#define IN_ROWS  12                // 8 + 2*2 y-halo
#define S1_ROWS  10                // 8 + 2*1
#define IN_P4    (IN_ROWS*ROW4)    // 384 f4 / input plane
#define S1_P4    (S1_ROWS*ROW4)    // 320 f4 / s1 plane
#define SLOT4(z) (((z)+8)&3)       // input ring: 4 slots
#define SLOT2(z) (((z)+8)&1)       // s1 ring: 2 slots

// Kernel A: softmax over C=4, subtract one-hot(target), square -> buf0.
// 4 float4 site-groups per thread. Zeros accs.
__global__ __launch_bounds__(256) void softmax_sq_kernel(
    const float* __restrict__ in, const int* __restrict__ tgt,
    float* __restrict__ out, double* __restrict__ accs)
{
    int tid = threadIdx.x;
    int gid = blockIdx.x * 256 + tid;
    if (gid < NACC) accs[gid] = 0.0;

    #pragma unroll
    for (int half = 0; half < 4; ++half) {
        int j4 = blockIdx.x * 1024 + half * 256 + tid;  // [0, NSITE/4)
        int base = j4 << 2;
        int b = base >> 21;
        int s = base & (DHW - 1);
        const float* p = in + (size_t)b * CDHW + s;

        float4 a0 = *(const float4*)(p);
        float4 a1 = *(const float4*)(p + DHW);
        float4 a2 = *(const float4*)(p + 2 * DHW);
        float4 a3 = *(const float4*)(p + 3 * DHW);
        int4   t  = *(const int4*)(tgt + base);

        float4 o0, o1, o2, o3;
        #define SOFTMAX1(K)                                                    \
        {                                                                      \
            float v0 = a0.K, v1 = a1.K, v2 = a2.K, v3 = a3.K;                  \
            float m  = fmaxf(fmaxf(v0, v1), fmaxf(v2, v3));                    \
            float e0 = expf(v0 - m), e1 = expf(v1 - m);                        \
            float e2 = expf(v2 - m), e3 = expf(v3 - m);                        \
            float inv = 1.0f / (e0 + e1 + e2 + e3);                            \
            int   tv = t.K;                                                    \
            float d0 = e0 * inv - (tv == 0 ? 1.0f : 0.0f);                     \
            float d1 = e1 * inv - (tv == 1 ? 1.0f : 0.0f);                     \
            float d2 = e2 * inv - (tv == 2 ? 1.0f : 0.0f);                     \
            float d3 = e3 * inv - (tv == 3 ? 1.0f : 0.0f);                     \
            o0.K = d0 * d0; o1.K = d1 * d1; o2.K = d2 * d2; o3.K = d3 * d3;    \
        }
        SOFTMAX1(x) SOFTMAX1(y) SOFTMAX1(z) SOFTMAX1(w)
        #undef SOFTMAX1

        float* q = out + (size_t)b * CDHW + s;
        *(float4*)(q)           = o0;
        *(float4*)(q + DHW)     = o1;
        *(float4*)(q + 2 * DHW) = o2;
        *(float4*)(q + 3 * DHW) = o3;
    }
}

// Kernel B: TWO fused erosion steps; z-marching rolling planes.
// Primary s1 row = trow+1 (always y-valid) so each thread's s2 center and
// z-neighbors live in a 3-deep register chain. Input ring = 4 slots, s1
// ring = 2 slots -> ONE barrier per plane. x-neighbors via lane shuffles.
__global__ __launch_bounds__(256, 4) void erode2_kernel(
    const float4* __restrict__ src, float4* __restrict__ dst,
    const float* __restrict__ kern, const float* __restrict__ bias,
    const float* __restrict__ weight, float c1, float c2,
    int store, double* __restrict__ accs)
{
    __shared__ float4 lin[4 * IN_P4];   // 24.6 KB
    __shared__ float4 ls1[2 * S1_P4];   // 10.2 KB
    __shared__ double wsum[4];

    const int tid = threadIdx.x;
    const int bid = blockIdx.x;
    const int y0 = (bid & 15) << 3;
    const int zb = ((bid >> 4) & 7) << 4;
    const int bc = bid >> 7;            // b*4 + c in [0,8)

    const float4* sp = src + ((size_t)bc << 19);   // slab = 2^19 f4
    float4*       dp = dst + ((size_t)bc << 19);
    const float wk = kern[13];          // all 7 taps equal
    const float bs = bias[bc & 3];

    const int col  = tid & 31;
    const int trow = tid >> 5;

    // ---- commit maps (input rows 0..11 <-> gy = y0+row-2) ----
    const int  gy0  = y0 + trow - 2;               // rows 0..7
    const bool lv0  = ((unsigned)gy0 < 128u);
    const int  off0 = (lv0 ? gy0 : 0) * 32 + col;
    const bool act1 = (tid < 128);                 // rows 8..11
    const int  gy1  = y0 + trow + 6;
    const bool lv1  = act1 && ((unsigned)gy1 < 128u);
    const int  off1 = (lv1 ? gy1 : 0) * 32 + col;

    // ---- s1 ragged rows {0,9} on tid<64 (primary row trow+1 is mask-free) --
    const bool  sact1 = (tid < 64);
    const int   sr  = (tid < 32) ? 0 : 9;
    const float m1  = ((unsigned)(y0 + sr - 1) < 128u) ? 1.f : 0.f;
    const int   ci1 = (sr + 1) * 32 + (tid & 31);  // input center for row sr
    const int   so1 = sr * 32 + (tid & 31);        // s1-plane store index

    const float lmask = (col == 0)  ? 0.f : 1.f;   // x=0 edge
    const float rmask = (col == 31) ? 0.f : 1.f;   // x=127 edge

    const int go4 = (y0 + trow) * 32 + col;        // owned global f4 offset

    const float4 f4z = make_float4(0.f, 0.f, 0.f, 0.f);
    float4 pf0 = f4z, pf1 = f4z;
    float4 s_m = f4z, s_c = f4z, s_p = f4z;        // s1 chain (rows trow+1)

    auto prefetch = [&](int L) {
        pf0 = f4z; pf1 = f4z;
        if ((unsigned)L < 128u) {
            const float4* zp = sp + ((size_t)L << 12);
            if (lv0) pf0 = zp[off0];
            if (lv1) pf1 = zp[off1];
        }
    };
    auto commit = [&](int L) {
        float4* sl = lin + SLOT4(L) * IN_P4;
        sl[tid] = pf0;
        if (act1) sl[256 + tid] = pf1;
    };
    // s1 at input center ci (reads c,u,d from pzc; m,p from pzm/pzp)
    auto s1one = [&](const float4* pzm, const float4* pzc, const float4* pzp,
                     int ci, float ym) -> float4 {
        float4 qC = pzc[ci];
        float4 qU = pzc[ci - 32];
        float4 qD = pzc[ci + 32];
        float4 qm = pzm[ci];
        float4 qp = pzp[ci];
        float lf = __shfl_up(qC.w, 1, 64)   * lmask;
        float rt = __shfl_down(qC.x, 1, 64) * rmask;
        float4 v;
        v.x = fmaxf((qC.x + lf   + qC.y + qU.x + qD.x + qm.x + qp.x) * wk + bs, 0.f) * ym;
        v.y = fmaxf((qC.y + qC.x + qC.z + qU.y + qD.y + qm.y + qp.y) * wk + bs, 0.f) * ym;
        v.z = fmaxf((qC.z + qC.y + qC.w + qU.z + qD.z + qm.z + qp.z) * wk + bs, 0.f) * ym;
        v.w = fmaxf((qC.w + qC.z + rt   + qU.w + qD.w + qm.w + qp.w) * wk + bs, 0.f) * ym;
        return v;
    };
    // computes s1 plane z (primary row trow+1 -> chain + LDS; ragged -> LDS)
    auto s1_phase = [&](int z) {
        float4* o = ls1 + SLOT2(z) * S1_P4;
        float4 vnew;
        if ((unsigned)z < 128u) {
            const float4* pzm = lin + SLOT4(z - 1) * IN_P4;
            const float4* pzc = lin + SLOT4(z)     * IN_P4;
            const float4* pzp = lin + SLOT4(z + 1) * IN_P4;
            vnew = s1one(pzm, pzc, pzp, tid + 64, 1.f);   // input row trow+2
            o[tid + 32] = vnew;                           // s1 row trow+1
            if (sact1) o[so1] = s1one(pzm, pzc, pzp, ci1, m1);
        } else {
            vnew = f4z;
            o[tid + 32] = f4z;
            if (sact1) o[so1] = f4z;
        }
        s_m = s_c; s_c = s_p; s_p = vnew;
    };

    double part = 0.0;

    // ---- prologue ----
    prefetch(zb - 2); commit(zb - 2);
    prefetch(zb - 1); commit(zb - 1);
    prefetch(zb);     commit(zb);
    prefetch(zb + 1);
    __syncthreads();
    s1_phase(zb - 1);                       // s_p = s1(zb-1)

    // ---- main loop: ONE barrier per plane ----
    for (int L = zb + 1; L <= zb + 17; ++L) {
        commit(L);                          // writes lin slot L&3
        if (L <= zb + 16) prefetch(L + 1);
        __syncthreads();
        s1_phase(L - 1);                    // reads lin L-2..L; writes ls1 (L-1)&1
        const int zo = L - 2;
        if (zo >= zb) {
            const float4* su = ls1 + SLOT2(zo) * S1_P4;   // written last iter
            float4 u4 = su[tid];            // s1 row trow
            float4 d4 = su[tid + 64];       // s1 row trow+2
            float lf = __shfl_up(s_c.w, 1, 64)   * lmask;
            float rt = __shfl_down(s_c.x, 1, 64) * rmask;
            float4 v;
            v.x = fmaxf((s_c.x + lf    + s_c.y + u4.x + d4.x + s_m.x + s_p.x) * wk + bs, 0.f);
            v.y = fmaxf((s_c.y + s_c.x + s_c.z + u4.y + d4.y + s_m.y + s_p.y) * wk + bs, 0.f);
            v.z = fmaxf((s_c.z + s_c.y + s_c.w + u4.z + d4.z + s_m.z + s_p.z) * wk + bs, 0.f);
            v.w = fmaxf((s_c.w + s_c.z + rt    + u4.w + d4.w + s_m.w + s_p.w) * wk + bs, 0.f);
            if (store) dp[((size_t)zo << 12) + go4] = v;
            float pl = c1 * (s_c.x + s_c.y + s_c.z + s_c.w)
                     + c2 * (v.x   + v.y   + v.z   + v.w);
            part += (double)pl;
        }
    }

    // ---- block reduction; slot bid is private to this block ----
    #pragma unroll
    for (int off = 32; off > 0; off >>= 1)
        part += __shfl_down(part, off, 64);
    if ((tid & 63) == 0) wsum[tid >> 6] = part;
    __syncthreads();
    if (tid == 0) {
        double tot = (wsum[0] + wsum[1] + wsum[2] + wsum[3]) * (double)weight[bc];
        atomicAdd(&accs[bid], tot);         // contention-free (private slot)
    }
}

// Reduce the NACC per-block accumulators -> scalar mean.
__global__ __launch_bounds__(1024) void finalize_kernel(
    const double* __restrict__ accs, float* __restrict__ out)
{
    __shared__ double wsum[16];
    double v = accs[threadIdx.x];
    #pragma unroll
    for (int off = 32; off > 0; off >>= 1)
        v += __shfl_down(v, off, 64);
    int lane = threadIdx.x & 63;
    int wid  = threadIdx.x >> 6;
    if (lane == 0) wsum[wid] = v;
    __syncthreads();
    if (threadIdx.x == 0) {
        double tot = 0.0;
        #pragma unroll
        for (int i = 0; i < 16; ++i) tot += wsum[i];
        out[0] = (float)(tot / (double)NTOT);
    }
}

extern "C" void kernel_launch(void* const* d_in, const int* in_sizes, int n_in,
                              void* d_out, int out_size, void* d_ws, size_t ws_size,
                              hipStream_t stream) {
    const float* in     = (const float*)d_in[0];
    const int*   tgt    = (const int*)d_in[1];
    const float* weight = (const float*)d_in[2];
    const float* kern   = (const float*)d_in[3];
    const float* bias   = (const float*)d_in[4];
    float* out = (float*)d_out;

    char* ws = (char*)d_ws;
    float* buf0 = (float*)ws;
    float* buf1 = (float*)(ws + (size_t)NTOT * sizeof(float));
    double* accs = (double*)(ws + (size_t)NTOT * 2 * sizeof(float));

    // 1) softmax + one-hot + square (also zeroes accs)
    softmax_sq_kernel<<<(NSITE / 16) / 256, 256, 0, stream>>>(in, tgt, buf0, accs);

    // 2) 5 fused double-erosion passes; last pass skips the store
    float* cur = buf0;
    float* nxt = buf1;
    for (int p = 0; p < 5; ++p) {
        float c1 = (float)((2 * p + 1) * (2 * p + 1));
        float c2 = (float)((2 * p + 2) * (2 * p + 2));
        int   store = (p < 4) ? 1 : 0;
        erode2_kernel<<<1024, 256, 0, stream>>>(
            (const float4*)cur, (float4*)nxt, kern, bias, weight, c1, c2, store, accs);
        float* t = cur; cur = nxt; nxt = t;
    }

    // 3) reduce + mean
    finalize_kernel<<<1, 1024, 0, stream>>>(accs, out);
}